// Round 6
// baseline (232.239 us; speedup 1.0000x reference)
//
#include <hip/hip_runtime.h>

#define N_ENT 40000
#define NB 64
#define BODY_LEN 3
#define N_REL 48
#define NUM_POS 24
#define THR 1e-20f

#define NBK 157          // buckets of 256 entities: ceil(40000/256)
#define PA_BLOCKS 320
#define STEP_BLOCKS 2048

// mem layout: entity-major, mem[ent*64 + b]
// item/CSR slot (DEST-major): uint2 { meta = src | (rEff<<16) | (ownerLow8<<24), val }
//   owner = DEST = bucket*256 + ownerLow8.
//   fwd message h->t (attn[r]):      owner=t, src=h, rEff=r
//   rev message t->h (attn[r+24]):   owner=h, src=t, rEff=r+24
//   killed edges stored with val=0.

// per-block bucket histogram -> pHist[block*NBK + bucket]  (no global atomics)
__global__ void k_hist(const int* __restrict__ eh, const int* __restrict__ et,
                       int* __restrict__ pHist, int nE) {
    __shared__ int h[NBK];
    int tid = threadIdx.x;
    for (int i = tid; i < NBK; i += 256) h[i] = 0;
    __syncthreads();
    int chunk = (nE + PA_BLOCKS - 1) / PA_BLOCKS;
    int b0 = blockIdx.x * chunk, b1 = min(nE, b0 + chunk);
    for (int i = b0 + tid; i < b1; i += 256) {
        atomicAdd(&h[et[i] >> 8], 1);   // fwd item: owner = tail
        atomicAdd(&h[eh[i] >> 8], 1);   // rev item: owner = head
    }
    __syncthreads();
    for (int i = tid; i < NBK; i += 256) pHist[blockIdx.x * NBK + i] = h[i];
}

// single block: bucket totals -> exclusive scan -> per-(block,bucket) absolute
// bases written back into pHist. Also zeroes act0/sums and seeds act0 with qh.
__global__ void k_bscan(int* __restrict__ pHist, int* __restrict__ bktBase,
                        int* __restrict__ offs, const int* __restrict__ qh,
                        unsigned char* __restrict__ act0, float* __restrict__ sums) {
    __shared__ int s[256];
    int t = threadIdx.x;
    int tot = 0;
    if (t < NBK) {
#pragma unroll 8
        for (int i = 0; i < PA_BLOCKS; ++i) tot += pHist[i * NBK + t];
    }
    s[t] = tot;
    __syncthreads();
    for (int off = 1; off < 256; off <<= 1) {
        int add = (t >= off) ? s[t - off] : 0;
        __syncthreads();
        s[t] += add;
        __syncthreads();
    }
    int ex = s[t] - tot;
    if (t < NBK) bktBase[t] = ex;
    if (t == NBK - 1) { bktBase[NBK] = s[t]; offs[N_ENT] = s[t]; }
    if (t < NBK) {
        int run = ex;
#pragma unroll 4
        for (int i = 0; i < PA_BLOCKS; ++i) {
            int c = pHist[i * NBK + t];
            pHist[i * NBK + t] = run;   // absolute base for block i, bucket t
            run += c;
        }
    }
    for (int i = t; i < N_ENT; i += 256) act0[i] = 0;
    for (int i = t; i < NB * 16; i += 256) sums[i] = 0.0f;
    __syncthreads();
    if (t < NB) act0[qh[t]] = 1;        // step-0 active sources = qh set
}

// bucket-grouped scatter using precomputed per-block bases (no global atomics).
// Kill-check folded in (killed stored with v=0).
__global__ void k_passA(const int* __restrict__ qh, const int* __restrict__ qr,
                        const int* __restrict__ tq, const int* __restrict__ eh,
                        const int* __restrict__ et, const int* __restrict__ er,
                        const float* __restrict__ ev, const int* __restrict__ pBase,
                        uint2* __restrict__ items, int nE) {
    __shared__ long long s_key[NB];
    __shared__ int cur[NBK];
    int tid = threadIdx.x;
    if (tid < NB)
        s_key[tid] = ((long long)qh[tid] << 32) | ((long long)tq[tid] << 8) | (long long)qr[tid];
    for (int i = tid; i < NBK; i += 256) cur[i] = pBase[blockIdx.x * NBK + i];
    __syncthreads();
    int chunk = (nE + PA_BLOCKS - 1) / PA_BLOCKS;   // MUST match k_hist
    int b0 = blockIdx.x * chunk, b1 = min(nE, b0 + chunk);
    for (int i = b0 + tid; i < b1; i += 256) {
        int hh = eh[i], te = et[i], r = er[i];
        long long k = ((long long)hh << 32) | ((long long)te << 8) | (long long)r;
        bool killed = false;
#pragma unroll
        for (int b = 0; b < NB; ++b) killed |= (s_key[b] == k);
        unsigned vb = killed ? 0u : __float_as_uint(ev[i]);
        int bk = te >> 8;                 // fwd: owner=te, src=hh, rEff=r
        int p = atomicAdd(&cur[bk], 1);
        items[p] = make_uint2((unsigned)hh | ((unsigned)r << 16) |
                              ((unsigned)(te & 255) << 24), vb);
        bk = hh >> 8;                     // rev: owner=hh, src=te, rEff=r+24
        p = atomicAdd(&cur[bk], 1);
        items[p] = make_uint2((unsigned)te | ((unsigned)(r + NUM_POS) << 16) |
                              ((unsigned)(hh & 255) << 24), vb);
    }
}

// one block per bucket: sort items by owner -> per-entity offs[] + final CSR.
__global__ void k_passB(const uint2* __restrict__ itemsA, const int* __restrict__ bktBase,
                        int* __restrict__ offs, uint2* __restrict__ csr) {
    __shared__ int cnt[256];
    __shared__ int sc[256];
    int tid = threadIdx.x;
    int b = blockIdx.x;
    int e0 = b << 8;
    int eCnt = min(256, N_ENT - e0);
    cnt[tid] = 0;
    __syncthreads();
    int ib = bktBase[b];
    int n = bktBase[b + 1] - ib;
    for (int i = tid; i < n; i += 256)
        atomicAdd(&cnt[itemsA[ib + i].x >> 24], 1);
    __syncthreads();
    int v = cnt[tid];
    sc[tid] = v;
    __syncthreads();
    for (int off = 1; off < 256; off <<= 1) {
        int add = (tid >= off) ? sc[tid - off] : 0;
        __syncthreads();
        sc[tid] += add;
        __syncthreads();
    }
    int ex = sc[tid] - v;
    if (tid < eCnt) offs[e0 + tid] = ib + ex;
    cnt[tid] = ex;                      // reuse as scatter cursor
    __syncthreads();
    for (int i = tid; i < n; i += 256) {
        uint2 it = itemsA[ib + i];
        int k = (int)(it.x >> 24);
        int p = atomicAdd(&cnt[k], 1);
        csr[ib + p] = it;
    }
}

// fused decay + message pass, DEST-major: one wave per dest entity.
// nxt[d] = old[d]*decay + sum over incoming items of old[src]*v*attn[rEff].
// No atomics on nxt (exclusive ownership). Writes next-step active[] bitmap.
// STEP==0: old is the analytic one-hot(qh). STEP==2: accumulates column sums.
template <int STEP>
__global__ __launch_bounds__(256) void k_step(
    const uint2* __restrict__ csr, const int* __restrict__ offs,
    const unsigned char* __restrict__ actIn, unsigned char* __restrict__ actOut,
    const float* __restrict__ attn, const float* __restrict__ oldm,
    const int* __restrict__ qh, float* __restrict__ nxt, float* __restrict__ sums) {
    __shared__ float s_attn[NB][N_REL + 1];  // stride 49: conflict-free
    __shared__ float s_dlast[NB];
    __shared__ int s_q[NB];
    __shared__ float s_s[NB];
    int tid = threadIdx.x, lane = tid & 63;
    for (int idx = tid; idx < NB * N_REL; idx += 256) {
        int b = idx / N_REL, r = idx % N_REL;
        s_attn[b][r] = attn[b * (BODY_LEN * N_REL) + STEP * N_REL + r];
    }
    if (tid < NB) {
        s_dlast[tid] = attn[tid * (BODY_LEN * N_REL) + STEP * N_REL + (N_REL - 1)];
        if (STEP == 0) s_q[tid] = qh[tid];
        if (STEP == 2) s_s[tid] = 0.0f;
    }
    __syncthreads();
    int myq = (STEP == 0) ? s_q[lane] : 0;
    float colsum = 0.0f;
    int w = (blockIdx.x * 256 + tid) >> 6;
    int nW = (gridDim.x * 256) >> 6;
    for (int d = w; d < N_ENT; d += nW) {
        float acc = 0.0f;
        if (STEP == 0) {
            acc = (myq == d) ? s_dlast[lane] : 0.0f;
        } else {
            if (actIn[d]) acc = oldm[(size_t)d * 64 + lane] * s_dlast[lane];
        }
        int base = offs[d];
        int cnt = offs[d + 1] - base;
        for (int k0 = 0; k0 < cnt; k0 += 64) {
            int i = k0 + lane;
            uint2 it = (i < cnt) ? csr[base + i] : make_uint2(0u, 0u);
            bool on = (i < cnt) && (it.y != 0u) && actIn[it.x & 0xFFFFu];
            unsigned long long m = __ballot(on);
            while (m) {
                int j = __ffsll((long long)m) - 1;
                m &= m - 1;
                unsigned mx = (unsigned)__shfl((int)it.x, j);
                float v = __uint_as_float((unsigned)__shfl((int)it.y, j));
                int s2 = (int)(mx & 0xFFFFu);
                float sv = (STEP == 0) ? ((myq == s2) ? 1.0f : 0.0f)
                                       : oldm[(size_t)s2 * 64 + lane];
                acc += sv * v * s_attn[lane][(mx >> 16) & 63];
            }
        }
        nxt[(size_t)d * 64 + lane] = acc;
        if (STEP < 2) {
            unsigned long long nz = __ballot(acc != 0.0f);
            if (lane == 0) actOut[d] = nz ? 1 : 0;
        }
        if (STEP == 2) colsum += acc;
    }
    if (STEP == 2) {
        atomicAdd(&s_s[lane], colsum);           // LDS: 4 waves -> 64 cells
        __syncthreads();
        if (tid < NB) atomicAdd(&sums[tid * 16], s_s[tid]);  // padded: own line each
    }
}

// transpose (ent-major -> batch-major) + normalize; block N_ENT/64 computes the loss
__global__ void k_norm_tr(const float* __restrict__ mem, const float* __restrict__ sums,
                          const int* __restrict__ tt, float* __restrict__ out) {
    if (blockIdx.x == N_ENT / 64) {  // loss block
        int b = threadIdx.x;
        if (b < 64) {
            float p = mem[(size_t)tt[b] * 64 + b] / fmaxf(THR, sums[b * 16]);
            float l = -logf(fmaxf(THR, p));
#pragma unroll
            for (int off = 32; off > 0; off >>= 1) l += __shfl_down(l, off);
            if (b == 0) out[0] = l * (1.0f / 64.0f);
        }
        return;
    }
    __shared__ float tile[64][65];
    __shared__ float s_inv[64];
    int tid = threadIdx.x;
    int e0 = blockIdx.x * 64;
    if (tid < 64) s_inv[tid] = 1.0f / fmaxf(THR, sums[tid * 16]);
    const float4* m4 = (const float4*)(mem + (size_t)e0 * 64);
#pragma unroll
    for (int k = 0; k < 4; ++k) {
        int i4 = k * 256 + tid;
        float4 v = m4[i4];
        int el = i4 >> 4, b0 = (i4 * 4) & 63;
        tile[el][b0 + 0] = v.x; tile[el][b0 + 1] = v.y;
        tile[el][b0 + 2] = v.z; tile[el][b0 + 3] = v.w;
    }
    __syncthreads();
#pragma unroll
    for (int k = 0; k < 16; ++k) {
        int idx = k * 256 + tid;
        int el = idx & 63, b = idx >> 6;
        out[1 + (size_t)b * N_ENT + e0 + el] = tile[el][b] * s_inv[b];
    }
}

extern "C" void kernel_launch(void* const* d_in, const int* in_sizes, int n_in,
                              void* d_out, int out_size, void* d_ws, size_t ws_size,
                              hipStream_t stream) {
    const int*   qh   = (const int*)d_in[0];
    const int*   qr   = (const int*)d_in[1];
    const int*   tt   = (const int*)d_in[2];
    const float* attn = (const float*)d_in[3];
    const int*   eh   = (const int*)d_in[4];
    const int*   et   = (const int*)d_in[5];
    const int*   er   = (const int*)d_in[6];
    const float* ev   = (const float*)d_in[7];
    float* out = (float*)d_out;
    int nE = in_sizes[4];

    const size_t MEM_BYTES = (size_t)NB * N_ENT * sizeof(float);  // 10,240,000
    char* ws = (char*)d_ws;
    int*   offs    = (int*)ws;                         // 160 KB
    int*   bktBase = (int*)(ws + (192u << 10));        // 640 B
    int*   pHist   = (int*)(ws + (196u << 10));        // 320*157*4 ~ 196 KB
    unsigned char* act0 = (unsigned char*)(ws + (452u << 10));  // 40 KB
    unsigned char* act1 = (unsigned char*)(ws + (512u << 10));  // 40 KB
    float* sums    = (float*)(ws + (576u << 10));      // 64*16 floats = 4 KB
    uint2* csr     = (uint2*)(ws + (1u << 20));        // 2*nE*8 = 4.8 MB
    float* memA    = (float*)(ws + (6u << 20));        // 10.24 MB
    float* memB;
    uint2* itemsA;
    size_t itemsBytes = (size_t)2 * nE * sizeof(uint2);
    size_t needBoth = (size_t)(6u << 20) + 2 * MEM_BYTES + itemsBytes;
    if (ws_size >= needBoth) {
        memB   = (float*)(ws + (6u << 20) + MEM_BYTES);
        itemsA = (uint2*)(ws + (6u << 20) + 2 * MEM_BYTES);
    } else {
        // out+1 (10.24 MB) reused with disjoint lifetimes: itemsA dies at
        // k_passB; memB first written by k_step<1>. k_norm_tr overwrites out.
        memB   = out + 1;
        itemsA = (uint2*)(out + 1);
    }

    // ---- dest-major CSR build (atomic-free global path) ----
    k_hist<<<PA_BLOCKS, 256, 0, stream>>>(eh, et, pHist, nE);
    k_bscan<<<1, 256, 0, stream>>>(pHist, bktBase, offs, qh, act0, sums);
    k_passA<<<PA_BLOCKS, 256, 0, stream>>>(qh, qr, tt, eh, et, er, ev, pHist, itemsA, nE);
    k_passB<<<NBK, 256, 0, stream>>>(itemsA, bktBase, offs, csr);

    // ---- fused decay+message steps, no atomics on mem ----
    k_step<0><<<STEP_BLOCKS, 256, 0, stream>>>(csr, offs, act0, act1, attn,
                                               nullptr, qh, memA, nullptr);
    k_step<1><<<STEP_BLOCKS, 256, 0, stream>>>(csr, offs, act1, act0, attn,
                                               memA, qh, memB, nullptr);
    k_step<2><<<STEP_BLOCKS, 256, 0, stream>>>(csr, offs, act0, nullptr, attn,
                                               memB, qh, memA, sums);

    k_norm_tr<<<N_ENT / 64 + 1, 256, 0, stream>>>(memA, sums, tt, out);
}

// Round 7
// 209.980 us; speedup vs baseline: 1.1060x; 1.1060x over previous
//
#include <hip/hip_runtime.h>

#define N_ENT 40000
#define NB 64
#define BODY_LEN 3
#define N_REL 48
#define NUM_POS 24
#define THR 1e-20f

#define NBK 313          // buckets of 128 entities: ceil(40000/128)
#define PA_BLOCKS 320
#define DEC_BLOCKS 320
#define FLIST_LDS 192    // per-block flagged-entity bound: 8 iters * 16 = 128

// mem layout: entity-major, mem[ent*64 + b]
// item/CSR slot (SOURCE-major): uint2 { meta = nbr | (rEff<<16) | (ownerLow7<<24), val }
//   owner = SRC = bucket*128 + ownerLow7.
//   fwd slot (in h's list): owner=h, nbr=t, rEff=r       (c = mem[h]*v*attn[r]     -> t)
//   rev slot (in t's list): owner=t, nbr=h, rEff=r+24    (c = mem[t]*v*attn[r+24]  -> h)
//   killed edges stored with val=0.

// fused dispatch 1: blocks [0,320) bucket-histogram; blocks [320,640) dense
// one-hot*decay0 init of memA + frontier0 (exact qh dedup) + zero fcnt/sums.
__global__ void k_build0(const int* __restrict__ eh, const int* __restrict__ et,
                         int* __restrict__ pHist, const int* __restrict__ qh,
                         const float* __restrict__ attn, float* __restrict__ memA,
                         int* __restrict__ fcnt, int* __restrict__ flist,
                         float* __restrict__ sums, int nE) {
    int tid = threadIdx.x;
    if (blockIdx.x < PA_BLOCKS) {
        __shared__ int h[NBK];
        for (int i = tid; i < NBK; i += 256) h[i] = 0;
        __syncthreads();
        int chunk = (nE + PA_BLOCKS - 1) / PA_BLOCKS;
        int b0 = blockIdx.x * chunk, b1 = min(nE, b0 + chunk);
        for (int i = b0 + tid; i < b1; i += 256) {
            atomicAdd(&h[eh[i] >> 7], 1);
            atomicAdd(&h[et[i] >> 7], 1);
        }
        __syncthreads();
        for (int i = tid; i < NBK; i += 256) pHist[blockIdx.x * NBK + i] = h[i];
    } else {
        __shared__ float s_d[NB];
        __shared__ int s_q[NB];
        if (tid < NB) {
            s_d[tid] = attn[tid * (BODY_LEN * N_REL) + 0 * N_REL + (N_REL - 1)];
            s_q[tid] = qh[tid];
        }
        __syncthreads();
        int ib = blockIdx.x - PA_BLOCKS;
        const int total4 = NB * N_ENT / 4;      // 640000
        for (int i4 = ib * 256 + tid; i4 < total4; i4 += 320 * 256) {
            int ent = (i4 * 4) >> 6;
            int b0 = (i4 * 4) & 63;
            float4 w;
            w.x = (s_q[b0 + 0] == ent) ? s_d[b0 + 0] : 0.0f;
            w.y = (s_q[b0 + 1] == ent) ? s_d[b0 + 1] : 0.0f;
            w.z = (s_q[b0 + 2] == ent) ? s_d[b0 + 2] : 0.0f;
            w.w = (s_q[b0 + 3] == ent) ? s_d[b0 + 3] : 0.0f;
            ((float4*)memA)[i4] = w;
        }
        if (ib == 0) {
            for (int i = tid; i < NB * 16; i += 256) sums[i] = 0.0f;
            if (tid < 64) {                      // wave 0: exact qh dedup
                int q = s_q[tid];
                bool first = true;
                for (int j = 0; j < tid; ++j) first &= (s_q[j] != q);
                unsigned long long mf = __ballot(first);
                int pos = __popcll(mf & ((1ULL << tid) - 1ULL));
                if (first) flist[pos] = q;
                if (tid == 0) fcnt[0] = __popcll(mf);
                if (tid == 1) fcnt[1] = 0;
                if (tid == 2) fcnt[2] = 0;
            }
        }
    }
}

// per-bucket column scan of pHist: relative exclusive bases + bucket total
__global__ void k_bcol(int* __restrict__ pHist, int* __restrict__ bktTot) {
    __shared__ int s[512];
    int t = threadIdx.x, b = blockIdx.x;
    int v = (t < PA_BLOCKS) ? pHist[t * NBK + b] : 0;
    s[t] = v;
    __syncthreads();
    for (int off = 1; off < 512; off <<= 1) {
        int add = (t >= off) ? s[t - off] : 0;
        __syncthreads();
        s[t] += add;
        __syncthreads();
    }
    if (t < PA_BLOCKS) pHist[t * NBK + b] = s[t] - v;
    if (t == PA_BLOCKS - 1) bktTot[b] = s[t];
}

// exclusive scan over 313 bucket totals -> bktBase[0..NBK]; offs[N_ENT] = total
__global__ void k_bscan_small(const int* __restrict__ bktTot, int* __restrict__ bktBase,
                              int* __restrict__ offs) {
    __shared__ int s[512];
    int t = threadIdx.x;
    int v = (t < NBK) ? bktTot[t] : 0;
    s[t] = v;
    __syncthreads();
    for (int off = 1; off < 512; off <<= 1) {
        int add = (t >= off) ? s[t - off] : 0;
        __syncthreads();
        s[t] += add;
        __syncthreads();
    }
    if (t < NBK) bktBase[t] = s[t] - v;
    if (t == NBK - 1) { bktBase[NBK] = s[t]; offs[N_ENT] = s[t]; }
}

// bucket-grouped scatter using precomputed per-(block,bucket) bases.
// Kill-check folded in (killed stored with v=0).
__global__ void k_passA(const int* __restrict__ qh, const int* __restrict__ qr,
                        const int* __restrict__ tq, const int* __restrict__ eh,
                        const int* __restrict__ et, const int* __restrict__ er,
                        const float* __restrict__ ev, const int* __restrict__ pBase,
                        const int* __restrict__ bktBase, uint2* __restrict__ items, int nE) {
    __shared__ long long s_key[NB];
    __shared__ int cur[NBK];
    int tid = threadIdx.x;
    if (tid < NB)
        s_key[tid] = ((long long)qh[tid] << 32) | ((long long)tq[tid] << 8) | (long long)qr[tid];
    for (int i = tid; i < NBK; i += 256)
        cur[i] = bktBase[i] + pBase[blockIdx.x * NBK + i];
    __syncthreads();
    int chunk = (nE + PA_BLOCKS - 1) / PA_BLOCKS;   // MUST match k_build0 hist
    int b0 = blockIdx.x * chunk, b1 = min(nE, b0 + chunk);
    for (int i = b0 + tid; i < b1; i += 256) {
        int hh = eh[i], te = et[i], r = er[i];
        long long k = ((long long)hh << 32) | ((long long)te << 8) | (long long)r;
        bool killed = false;
#pragma unroll
        for (int b = 0; b < NB; ++b) killed |= (s_key[b] == k);
        unsigned vb = killed ? 0u : __float_as_uint(ev[i]);
        int bk = hh >> 7;                 // fwd slot: owner=h
        int p = atomicAdd(&cur[bk], 1);
        items[p] = make_uint2((unsigned)te | ((unsigned)r << 16) |
                              ((unsigned)(hh & 127) << 24), vb);
        bk = te >> 7;                     // rev slot: owner=t
        p = atomicAdd(&cur[bk], 1);
        items[p] = make_uint2((unsigned)hh | ((unsigned)(r + NUM_POS) << 16) |
                              ((unsigned)(te & 127) << 24), vb);
    }
}

// one block per bucket (128 entities): owner histogram -> scan ->
// per-entity offs[] -> scatter into final CSR (block-private contiguous span).
__global__ void k_passB(const uint2* __restrict__ itemsA, const int* __restrict__ bktBase,
                        int* __restrict__ offs, uint2* __restrict__ csr) {
    __shared__ int cnt[128];
    __shared__ int sc[256];
    int tid = threadIdx.x;
    int b = blockIdx.x;
    int e0 = b << 7;
    int eCnt = min(128, N_ENT - e0);
    if (tid < 128) cnt[tid] = 0;
    __syncthreads();
    int ib = bktBase[b];
    int n = bktBase[b + 1] - ib;
    for (int i = tid; i < n; i += 256)
        atomicAdd(&cnt[itemsA[ib + i].x >> 24], 1);
    __syncthreads();
    int v = (tid < 128) ? cnt[tid] : 0;
    sc[tid] = v;
    __syncthreads();
    for (int off = 1; off < 256; off <<= 1) {
        int add = (tid >= off) ? sc[tid - off] : 0;
        __syncthreads();
        sc[tid] += add;
        __syncthreads();
    }
    int ex = sc[tid] - v;
    if (tid < eCnt) offs[e0 + tid] = ib + ex;
    if (tid < 128) cnt[tid] = ex;       // reuse as scatter cursor
    __syncthreads();
    for (int i = tid; i < n; i += 256) {
        uint2 it = itemsA[ib + i];
        int k = (int)(it.x >> 24);
        int p = atomicAdd(&cnt[k], 1);
        csr[ib + p] = it;
    }
}

// ---- frontier aggregation (block-local; ONE global atomic per block) ----
__device__ __forceinline__ void flag_entities(unsigned long long m, int lane,
                                              int ent, int* s_cnt, int* s_list) {
    bool flag = ((lane & 15) == 0) && ((m >> lane) & 0xFFFFULL);
    unsigned long long am = __ballot(flag);
    if (am) {
        int leader = __ffsll((long long)am) - 1;
        int lb = 0;
        if (lane == leader) lb = atomicAdd(s_cnt, __popcll(am));
        lb = __shfl(lb, leader);
        if (flag) {
            int rank = __popcll(am & ((1ULL << lane) - 1ULL));
            s_list[lb + rank] = ent;
        }
    }
}

// nxt = old * decay; appends frontier of entities with any nonzero lane in old.
// When sums != nullptr, also accumulates column sums of the DECAYED output.
__global__ void k_decay(const float* __restrict__ oldm, float* __restrict__ nxt,
                        const float* __restrict__ attn, int step,
                        int* __restrict__ fcnt, int* __restrict__ flist,
                        float* __restrict__ sums) {
    __shared__ float s_d[NB];
    __shared__ float s_s[NB];
    __shared__ int s_list[FLIST_LDS];
    __shared__ int s_cnt, s_gbase;
    int tid = threadIdx.x;
    if (tid < NB) {
        s_d[tid] = attn[tid * (BODY_LEN * N_REL) + step * N_REL + (N_REL - 1)];
        s_s[tid] = 0.0f;
    }
    if (tid == 0) s_cnt = 0;
    __syncthreads();
    int lane = tid & 63;
    int b0 = (tid * 4) & 63;
    float cs0 = 0.0f, cs1 = 0.0f, cs2 = 0.0f, cs3 = 0.0f;
    const int total4 = NB * N_ENT / 4;       // 640000
    for (int i4 = blockIdx.x * 256 + tid; i4 < total4; i4 += gridDim.x * 256) {
        float4 v = ((const float4*)oldm)[i4];
        float4 w;
        w.x = v.x * s_d[b0 + 0];
        w.y = v.y * s_d[b0 + 1];
        w.z = v.z * s_d[b0 + 2];
        w.w = v.w * s_d[b0 + 3];
        ((float4*)nxt)[i4] = w;
        if (sums) { cs0 += w.x; cs1 += w.y; cs2 += w.z; cs3 += w.w; }
        bool nz = (v.x != 0.0f) | (v.y != 0.0f) | (v.z != 0.0f) | (v.w != 0.0f);
        unsigned long long m = __ballot(nz);
        flag_entities(m, lane, (i4 * 4) >> 6, &s_cnt, s_list);
    }
    __syncthreads();
    if (tid == 0 && s_cnt) s_gbase = atomicAdd(fcnt, s_cnt);
    __syncthreads();
    for (int i = tid; i < s_cnt; i += 256) flist[s_gbase + i] = s_list[i];
    if (sums) {
        atomicAdd(&s_s[b0 + 0], cs0);
        atomicAdd(&s_s[b0 + 1], cs1);
        atomicAdd(&s_s[b0 + 2], cs2);
        atomicAdd(&s_s[b0 + 3], cs3);
        __syncthreads();
        if (tid < NB) atomicAdd(&sums[tid * 16], s_s[tid]);
    }
}

// frontier-centric message pass: one wave per active source entity.
// When sums != nullptr, accumulates column sums of the atomic contributions.
template <bool STEP0>
__global__ __launch_bounds__(256) void k_fstep(
    const uint2* __restrict__ csr, const int* __restrict__ offs,
    const int* __restrict__ flist, const int* __restrict__ fcnt,
    const float* __restrict__ attn, int step,
    const float* __restrict__ oldm, const int* __restrict__ qh,
    float* __restrict__ nxt, float* __restrict__ sums) {
    __shared__ float s_attn[NB][N_REL + 1];  // stride 49: conflict-free
    __shared__ float s_s[NB];
    int tid = threadIdx.x;
    for (int idx = tid; idx < NB * N_REL; idx += 256) {
        int b = idx / N_REL, r = idx % N_REL;
        s_attn[b][r] = attn[b * (BODY_LEN * N_REL) + step * N_REL + r];
    }
    if (tid < NB) s_s[tid] = 0.0f;
    __syncthreads();
    int lane = tid & 63;
    int myqh = STEP0 ? qh[lane] : 0;
    float colsum = 0.0f;
    int n = *fcnt;
    int w = (blockIdx.x * 256 + tid) >> 6;
    int nW = (gridDim.x * 256) >> 6;
    for (int f = w; f < n; f += nW) {
        int e = flist[f];
        float src = STEP0 ? ((myqh == e) ? 1.0f : 0.0f)
                          : oldm[(size_t)e * 64 + lane];
        int base = offs[e];
        int cnt = offs[e + 1] - base;
        for (int k0 = 0; k0 < cnt; k0 += 64) {
            uint2 slot = make_uint2(0u, 0u);
            if (k0 + lane < cnt) slot = csr[base + k0 + lane];
            int lim = min(64, cnt - k0);
            for (int j = 0; j < lim; ++j) {
                unsigned meta = (unsigned)__shfl((int)slot.x, j);
                float v = __uint_as_float((unsigned)__shfl((int)slot.y, j));
                if (v == 0.0f) continue;  // killed edge (wave-uniform)
                float val = src * v * s_attn[lane][(meta >> 16) & 63];
                if (val != 0.0f) {
                    atomicAdd(&nxt[(size_t)(meta & 0xFFFFu) * 64 + lane], val);
                    if (sums) colsum += val;
                }
            }
        }
    }
    if (sums) {
        atomicAdd(&s_s[lane], colsum);
        __syncthreads();
        if (tid < NB) atomicAdd(&sums[tid * 16], s_s[tid]);
    }
}

// transpose (ent-major -> batch-major) + normalize; block N_ENT/64 computes the loss
__global__ void k_norm_tr(const float* __restrict__ mem, const float* __restrict__ sums,
                          const int* __restrict__ tt, float* __restrict__ out) {
    if (blockIdx.x == N_ENT / 64) {  // loss block
        int b = threadIdx.x;
        if (b < 64) {
            float p = mem[(size_t)tt[b] * 64 + b] / fmaxf(THR, sums[b * 16]);
            float l = -logf(fmaxf(THR, p));
#pragma unroll
            for (int off = 32; off > 0; off >>= 1) l += __shfl_down(l, off);
            if (b == 0) out[0] = l * (1.0f / 64.0f);
        }
        return;
    }
    __shared__ float tile[64][65];
    __shared__ float s_inv[64];
    int tid = threadIdx.x;
    int e0 = blockIdx.x * 64;
    if (tid < 64) s_inv[tid] = 1.0f / fmaxf(THR, sums[tid * 16]);
    const float4* m4 = (const float4*)(mem + (size_t)e0 * 64);
#pragma unroll
    for (int k = 0; k < 4; ++k) {
        int i4 = k * 256 + tid;
        float4 v = m4[i4];
        int el = i4 >> 4, b0 = (i4 * 4) & 63;
        tile[el][b0 + 0] = v.x; tile[el][b0 + 1] = v.y;
        tile[el][b0 + 2] = v.z; tile[el][b0 + 3] = v.w;
    }
    __syncthreads();
#pragma unroll
    for (int k = 0; k < 16; ++k) {
        int idx = k * 256 + tid;
        int el = idx & 63, b = idx >> 6;
        out[1 + (size_t)b * N_ENT + e0 + el] = tile[el][b] * s_inv[b];
    }
}

extern "C" void kernel_launch(void* const* d_in, const int* in_sizes, int n_in,
                              void* d_out, int out_size, void* d_ws, size_t ws_size,
                              hipStream_t stream) {
    const int*   qh   = (const int*)d_in[0];
    const int*   qr   = (const int*)d_in[1];
    const int*   tt   = (const int*)d_in[2];
    const float* attn = (const float*)d_in[3];
    const int*   eh   = (const int*)d_in[4];
    const int*   et   = (const int*)d_in[5];
    const int*   er   = (const int*)d_in[6];
    const float* ev   = (const float*)d_in[7];
    float* out = (float*)d_out;
    int nE = in_sizes[4];

    const size_t MEM_BYTES = (size_t)NB * N_ENT * sizeof(float);  // 10,240,000
    char* ws = (char*)d_ws;
    int*   offs    = (int*)ws;                         // 160 KB
    int*   flist   = (int*)(ws + (192u << 10));        // 160 KB
    int*   pHist   = (int*)(ws + (384u << 10));        // 320*313*4 ~ 400 KB
    int*   bktTot  = (int*)(ws + (896u << 10));        // 313*4
    int*   bktBase = (int*)(ws + (900u << 10));        // 314*4
    int*   fcnt    = (int*)(ws + (904u << 10));        // 12 B
    float* sums    = (float*)(ws + (908u << 10));      // 64*16 floats = 4 KB
    uint2* csr     = (uint2*)(ws + (1u << 20));        // 2*nE*8 = 4.8 MB
    float* memA    = (float*)(ws + (6u << 20));        // 10.24 MB
    float* memB;
    uint2* itemsA;
    size_t itemsBytes = (size_t)2 * nE * sizeof(uint2);
    size_t needBoth = (size_t)(6u << 20) + 2 * MEM_BYTES + itemsBytes;
    if (ws_size >= needBoth) {
        memB   = (float*)(ws + (6u << 20) + MEM_BYTES);
        itemsA = (uint2*)(ws + (6u << 20) + 2 * MEM_BYTES);
    } else {
        // out+1 (10.24 MB) reused with disjoint lifetimes: itemsA dies at
        // k_passB; memB first written by k_decay step 1. k_norm_tr overwrites out.
        memB   = out + 1;
        itemsA = (uint2*)(out + 1);
    }

    // ---- build: hist+init fused, parallel base computation, bucket sort ----
    k_build0<<<2 * PA_BLOCKS, 256, 0, stream>>>(eh, et, pHist, qh, attn, memA,
                                                fcnt, flist, sums, nE);
    k_bcol<<<NBK, 512, 0, stream>>>(pHist, bktTot);
    k_bscan_small<<<1, 512, 0, stream>>>(bktTot, bktBase, offs);
    k_passA<<<PA_BLOCKS, 256, 0, stream>>>(qh, qr, tt, eh, et, er, ev, pHist,
                                           bktBase, itemsA, nE);
    k_passB<<<NBK, 256, 0, stream>>>(itemsA, bktBase, offs, csr);

    // ---- step 0: virtual one-hot source; atomics into dense-initialized memA ----
    k_fstep<true><<<16, 256, 0, stream>>>(csr, offs, flist, fcnt + 0, attn, 0,
                                          nullptr, qh, memA, nullptr);
    // ---- step 1: memA -> memB ----
    k_decay<<<DEC_BLOCKS, 256, 0, stream>>>(memA, memB, attn, 1, fcnt + 1, flist, nullptr);
    k_fstep<false><<<1024, 256, 0, stream>>>(csr, offs, flist, fcnt + 1, attn, 1,
                                             memA, nullptr, memB, nullptr);
    // ---- step 2: memB -> memA, with fused column sums ----
    k_decay<<<DEC_BLOCKS, 256, 0, stream>>>(memB, memA, attn, 2, fcnt + 2, flist, sums);
    k_fstep<false><<<1024, 256, 0, stream>>>(csr, offs, flist, fcnt + 2, attn, 2,
                                             memB, nullptr, memA, sums);

    k_norm_tr<<<N_ENT / 64 + 1, 256, 0, stream>>>(memA, sums, tt, out);
}